// Round 4
// baseline (61.867 us; speedup 1.0000x reference)
//
#include <hip/hip_runtime.h>

#define N_SAMPLES 128

// DPP ctrl encodings (gfx9/CDNA)
#define DPP_ROW_SHR1  0x111
#define DPP_ROW_SHR2  0x112
#define DPP_ROW_SHR4  0x114
#define DPP_ROW_SHR8  0x118
#define DPP_ROW_ROR4  0x124
#define DPP_ROW_ROR8  0x128
#define DPP_BCAST15   0x142  // broadcast lane15 of each row to the NEXT row
#define DPP_QUAD_XOR1 0xB1   // quad_perm [1,0,3,2]
#define DPP_QUAD_XOR2 0x4E   // quad_perm [2,3,0,1]

// DPP-shifted value with multiplicative identity (1.0) in lanes whose source
// is invalid OR whose row is masked off (those lanes yield `old`).
template <int CTRL, int ROWMASK>
__device__ __forceinline__ float dpp_shift_id1(float src) {
    int s = __builtin_bit_cast(int, src);
    int o = __builtin_bit_cast(int, 1.0f);
    int r = __builtin_amdgcn_update_dpp(o, s, CTRL, ROWMASK, 0xF, false);
    return __builtin_bit_cast(float, r);
}

// Plain DPP move (all-valid patterns: quad_perm, row_ror)
template <int CTRL>
__device__ __forceinline__ float dpp_mov(float src) {
    int r = __builtin_amdgcn_mov_dpp(__builtin_bit_cast(int, src), CTRL, 0xF, 0xF, true);
    return __builtin_bit_cast(float, r);
}

// Sum across a 16-lane row entirely on the DPP pipe (all lanes get row sum).
__device__ __forceinline__ float row16_sum(float x) {
    x += dpp_mov<DPP_QUAD_XOR1>(x);
    x += dpp_mov<DPP_QUAD_XOR2>(x);
    x += dpp_mov<DPP_ROW_ROR4>(x);
    x += dpp_mov<DPP_ROW_ROR8>(x);
    return x;
}

// Cross the row boundary within a 32-lane group: lane ^ 16 (BitMode swizzle).
__device__ __forceinline__ float swz_xor16(float x) {
    int r = __builtin_amdgcn_ds_swizzle(__builtin_bit_cast(int, x), 0x401F);
    return __builtin_bit_cast(float, r);
}

__global__ __launch_bounds__(256) void volrender_kernel(
    const float* __restrict__ depth,
    const float* __restrict__ rgb,
    const float* __restrict__ sigma,
    float* __restrict__ out_color,
    float* __restrict__ out_depth,
    int n_rays)
{
    // 32 lanes per ray, 4 samples per lane. 2 rays per wave, 8 rays per block.
    const int tid   = threadIdx.x;
    const int llane = tid & 31;
    const int ray   = blockIdx.x * 8 + (tid >> 5);
    if (ray >= n_rays) return;

    const size_t base = (size_t)ray * N_SAMPLES;

    float4 d = *reinterpret_cast<const float4*>(depth + base + 4 * llane);
    float4 s = *reinterpret_cast<const float4*>(sigma + base + 4 * llane);

    // delta[i] = d[i+1] - d[i]; sample 127 padded with 1e10
    float dnext  = __shfl_down(d.x, 1, 32);
    float delta0 = d.y - d.x;
    float delta1 = d.z - d.y;
    float delta2 = d.w - d.z;
    float delta3 = (llane == 31) ? 1e10f : (dnext - d.w);

    const float EPS = 1e-10f;
    float e0 = __expf(-fmaxf(s.x, 0.0f) * delta0);
    float e1 = __expf(-fmaxf(s.y, 0.0f) * delta1);
    float e2 = __expf(-fmaxf(s.z, 0.0f) * delta2);
    float e3 = __expf(-fmaxf(s.w, 0.0f) * delta3);
    float a0 = 1.0f - e0, a1 = 1.0f - e1, a2 = 1.0f - e2, a3 = 1.0f - e3;
    float t0 = e0 + EPS, t1 = e1 + EPS, t2 = e2 + EPS, t3 = e3 + EPS;

    // --- 32-lane exclusive multiplicative scan of per-lane product, all DPP ---
    float rowincl = t0 * t1 * t2 * t3;
    rowincl *= dpp_shift_id1<DPP_ROW_SHR1, 0xF>(rowincl);
    rowincl *= dpp_shift_id1<DPP_ROW_SHR2, 0xF>(rowincl);
    rowincl *= dpp_shift_id1<DPP_ROW_SHR4, 0xF>(rowincl);
    rowincl *= dpp_shift_id1<DPP_ROW_SHR8, 0xF>(rowincl);  // within-row-16 inclusive
    // BCAST15 writes NEXT row: row1<-lane15, row2<-lane31(!), row3<-lane47.
    // row_mask=0xA enables only rows 1 and 3; rows 0,2 keep old=1.0 — this
    // keeps the two 32-lane rays in the wave independent.
    float b       = dpp_shift_id1<DPP_BCAST15, 0xA>(rowincl);
    float rowexcl = dpp_shift_id1<DPP_ROW_SHR1, 0xF>(rowincl); // lane0 of each row <- 1.0
    float excl    = rowexcl * b;                               // exact 32-lane exclusive prefix

    float w0 = a0 * excl;
    float pre1 = excl * t0;
    float w1 = a1 * pre1;
    float pre2 = pre1 * t1;
    float w2 = a2 * pre2;
    float w3 = a3 * pre2 * t2;

    // rgb: 12 contiguous floats per lane at ray*384 + 12*llane (16B-aligned)
    const float* rbase = rgb + (size_t)ray * (N_SAMPLES * 3) + llane * 12;
    float4 q0 = *reinterpret_cast<const float4*>(rbase);      // R0 G0 B0 R1
    float4 q1 = *reinterpret_cast<const float4*>(rbase + 4);  // G1 B1 R2 G2
    float4 q2 = *reinterpret_cast<const float4*>(rbase + 8);  // B2 R3 G3 B3

    auto sigmoid = [](float x) { return 1.0f / (1.0f + __expf(-x)); };

    float c0 = w0 * sigmoid(q0.x) + w1 * sigmoid(q0.w) + w2 * sigmoid(q1.z) + w3 * sigmoid(q2.y);
    float c1 = w0 * sigmoid(q0.y) + w1 * sigmoid(q1.x) + w2 * sigmoid(q1.w) + w3 * sigmoid(q2.z);
    float c2 = w0 * sigmoid(q0.z) + w1 * sigmoid(q1.y) + w2 * sigmoid(q2.x) + w3 * sigmoid(q2.w);
    float dd = w0 * d.x + w1 * d.y + w2 * d.z + w3 * d.w;

    // --- reduce across the 32-lane group: DPP row sum + one xor16 swizzle each ---
    c0 = row16_sum(c0); c0 += swz_xor16(c0);
    c1 = row16_sum(c1); c1 += swz_xor16(c1);
    c2 = row16_sum(c2); c2 += swz_xor16(c2);
    dd = row16_sum(dd); dd += swz_xor16(dd);

    if (llane == 0) {
        out_color[(size_t)ray * 3 + 0] = c0;
        out_color[(size_t)ray * 3 + 1] = c1;
        out_color[(size_t)ray * 3 + 2] = c2;
        out_depth[ray] = dd;
    }
}

extern "C" void kernel_launch(void* const* d_in, const int* in_sizes, int n_in,
                              void* d_out, int out_size, void* d_ws, size_t ws_size,
                              hipStream_t stream)
{
    const float* depth = (const float*)d_in[0];
    const float* rgb   = (const float*)d_in[1];
    const float* sigma = (const float*)d_in[2];

    const int n_rays = in_sizes[0] / N_SAMPLES;

    float* out_color = (float*)d_out;                      // [n_rays, 3]
    float* out_depth = out_color + (size_t)n_rays * 3;     // [n_rays, 1]

    const int rays_per_block = 8;  // 256 threads, 32 lanes/ray
    const int blocks = (n_rays + rays_per_block - 1) / rays_per_block;

    hipLaunchKernelGGL(volrender_kernel, dim3(blocks), dim3(256), 0, stream,
                       depth, rgb, sigma, out_color, out_depth, n_rays);
}